// Round 14
// baseline (168.964 us; speedup 1.0000x reference)
//
#include <hip/hip_runtime.h>
#include <stdint.h>

typedef __attribute__((ext_vector_type(8))) short bf16x8;
typedef __attribute__((ext_vector_type(4))) float f32x4;
typedef __attribute__((ext_vector_type(16))) float f32x16;
typedef __attribute__((ext_vector_type(8))) unsigned short ushort8;
typedef __attribute__((ext_vector_type(4))) unsigned short ushort4v;

#define MFMA16(a, b, c) __builtin_amdgcn_mfma_f32_16x16x32_bf16((a), (b), (c), 0, 0, 0)
#define MFMA32(a, b, c) __builtin_amdgcn_mfma_f32_32x32x16_bf16((a), (b), (c), 0, 0, 0)

// B=8, S=1024, D=1024, H=16, DK=64
#define SLEN 1024
#define NHEAD 16
#define HDIM 64
#define DMODEL 1024
#define NROWS 8192  // B*S
#define LOG2E 1.44269504088896340736f

__device__ __forceinline__ unsigned short f2bf(float f) {
  unsigned int u = __float_as_uint(f);
  u += 0x7FFFu + ((u >> 16) & 1u);   // RNE
  return (unsigned short)(u >> 16);
}

__device__ __forceinline__ float fast_exp2(float x) {
#if __has_builtin(__builtin_amdgcn_exp2f)
  return __builtin_amdgcn_exp2f(x);
#else
  float r; asm("v_exp_f32 %0, %1" : "=v"(r) : "v"(x)); return r;
#endif
}

__device__ __forceinline__ unsigned int cvt_pk_bf16(float lo, float hi) {
  unsigned int r;
  asm("v_cvt_pk_bf16_f32 %0, %1, %2" : "=v"(r) : "v"(lo), "v"(hi));
  return r;
}

// async global->LDS, 16B per lane; LDS dest = wave-uniform base + lane*16 (HW).
__device__ __forceinline__ void gload_lds16(const void* g, void* l) {
  __builtin_amdgcn_global_load_lds(
      (const __attribute__((address_space(1))) void*)g,
      (__attribute__((address_space(3))) void*)l, 16, 0, 0);
}

// ---------------- fused prep: convert X, transpose weights, bias table ----------------
__global__ __launch_bounds__(256) void k_prep(
    const float* __restrict__ x, unsigned short* __restrict__ xb,
    const float* __restrict__ w0, const float* __restrict__ w1,
    const float* __restrict__ w2, const float* __restrict__ w3,
    unsigned short* __restrict__ o0, unsigned short* __restrict__ o1,
    unsigned short* __restrict__ o2, unsigned short* __restrict__ o3,
    const float* __restrict__ rel_bias, float* __restrict__ bt) {
  const int bi = blockIdx.x;
  const int tid = threadIdx.x;
  if (bi < 4096) {
    int idx = (bi * 256 + tid) * 8;
    float4 a = *(const float4*)(x + idx);
    float4 b = *(const float4*)(x + idx + 4);
    ushort8 o;
    o[0] = f2bf(a.x); o[1] = f2bf(a.y); o[2] = f2bf(a.z); o[3] = f2bf(a.w);
    o[4] = f2bf(b.x); o[5] = f2bf(b.y); o[6] = f2bf(b.z); o[7] = f2bf(b.w);
    *(ushort8*)(xb + idx) = o;
  } else if (bi < 8192) {
    const int t = bi - 4096;
    const int z = t >> 10;
    const float* w = (z == 0) ? w0 : (z == 1) ? w1 : (z == 2) ? w2 : w3;
    unsigned short* o = (z == 0) ? o0 : (z == 1) ? o1 : (z == 2) ? o2 : o3;
    __shared__ unsigned short tile[32][33];
    const int bx = t & 31, by = (t & 1023) >> 5;
#pragma unroll
    for (int p = 0; p < 4; ++p) {
      int idx = tid + p * 256;
      int r = idx >> 5, c = idx & 31;
      tile[r][c] = f2bf(w[(size_t)(by * 32 + r) * DMODEL + bx * 32 + c]);
    }
    __syncthreads();
#pragma unroll
    for (int p = 0; p < 4; ++p) {
      int idx = tid + p * 256;
      int r = idx >> 5, c = idx & 31;
      o[(size_t)(bx * 32 + r) * DMODEL + by * 32 + c] = tile[c][r];
    }
  } else {
    int i = (bi - 8192) * 256 + tid;
    if (i >= NHEAD * 2047) return;
    int h = i / 2047, rdx = i % 2047;
    int rel = rdx - 1023;
    int rb = (rel > 0) ? 16 : 0;
    int rp = (rel < 0) ? -rel : rel;
    int bucket;
    if (rp < 8) {
      bucket = rb + rp;
    } else {
      int large;
      if (rp >= 91) {
        large = 15;
      } else {
        int nb = 31 - __clz(rp);
        long long sq = (long long)rp * rp;
        int f2 = 2 * nb + ((sq >= (1LL << (2 * nb + 1))) ? 1 : 0);
        large = 8 + (f2 - 6);
        if (large > 15) large = 15;
      }
      bucket = rb + large;
    }
    bt[h * 2048 + rdx] = rel_bias[bucket * 16 + h] * LOG2E;
  }
}

// ---------------- 2-phase GEMM core, BK=64, XOR-swizzled LDS (R10-verified) ----------------
__device__ __forceinline__ void gemm_tile_lds(const unsigned short* __restrict__ A,
                                              const unsigned short* __restrict__ Bt,
                                              int K, int tm, int tn,
                                              unsigned short* As, unsigned short* Bs,
                                              f32x4 acc[4][4]) {
  const int tid = threadIdx.x;
  const int lane = tid & 63;
  const int w = tid >> 6;
  const int wr = w >> 1, wc = w & 1;
  const int g = lane >> 4, t = lane & 15;
  const int NKT = K >> 6;   // BK=64

  auto stageT = [&](int bufo, int ko) {
#pragma unroll
    for (int j = 0; j < 4; ++j) {
      const int r = w * 32 + j * 8 + (lane >> 3);
      const int lc = (lane & 7) ^ (r & 7);
      gload_lds16(A + (size_t)(tm + r) * K + ko + lc * 8, As + bufo + (w * 4 + j) * 512);
      gload_lds16(Bt + (size_t)(tn + r) * K + ko + lc * 8, Bs + bufo + (w * 4 + j) * 512);
    }
  };

  f32x4 z = {0.f, 0.f, 0.f, 0.f};
#pragma unroll
  for (int mi = 0; mi < 4; ++mi)
#pragma unroll
    for (int ni = 0; ni < 4; ++ni) acc[mi][ni] = z;

  stageT(0, 0);
  __syncthreads();

#pragma unroll 1
  for (int kt = 0; kt < NKT; ++kt) {
    const int cur = (kt & 1) * 8192;
    if (kt + 1 < NKT) stageT(cur ^ 8192, (kt + 1) * 64);

    bf16x8 af[2][4], bfr[2][4];
#pragma unroll
    for (int kk = 0; kk < 2; ++kk)
#pragma unroll
      for (int mi = 0; mi < 4; ++mi) {
        const int ra = wr * 64 + mi * 16 + t;
        const int pa = ((kk << 2) | g) ^ (ra & 7);
        af[kk][mi] = *(const bf16x8*)&As[cur + ra * 64 + pa * 8];
      }
#pragma unroll
    for (int kk = 0; kk < 2; ++kk)
#pragma unroll
      for (int ni = 0; ni < 4; ++ni) {
        const int rb = wc * 64 + ni * 16 + t;
        const int pb = ((kk << 2) | g) ^ (rb & 7);
        bfr[kk][ni] = *(const bf16x8*)&Bs[cur + rb * 64 + pb * 8];
      }
#pragma unroll
    for (int kk = 0; kk < 2; ++kk)
#pragma unroll
      for (int mi = 0; mi < 4; ++mi)
#pragma unroll
        for (int ni = 0; ni < 4; ++ni)
          acc[mi][ni] = MFMA16(af[kk][mi], bfr[kk][ni], acc[mi][ni]);

    __syncthreads();
  }
}

// ---------------- QKV projection ----------------
__global__ __launch_bounds__(256) void k_gemm_qkv(
    const unsigned short* __restrict__ Xb,
    const unsigned short* __restrict__ Wqt, const unsigned short* __restrict__ Wkt,
    const unsigned short* __restrict__ Wvt,
    unsigned short* __restrict__ Qb, unsigned short* __restrict__ Kb,
    unsigned short* __restrict__ Vt) {
  __shared__ alignas(16) unsigned short As[2 * 128 * 64];
  __shared__ alignas(16) unsigned short Bs[2 * 128 * 64];
  int z = blockIdx.z;
  const unsigned short* Bt = (z == 0) ? Wqt : (z == 1) ? Wkt : Wvt;
  const int wid = (blockIdx.x & 7) * 64 + (blockIdx.x >> 3);
  int tm = (wid >> 3) * 128, tn = (wid & 7) * 128;
  f32x4 acc[4][4];
  gemm_tile_lds(Xb, Bt, DMODEL, tm, tn, As, Bs, acc);

  const int lane = threadIdx.x & 63, w = threadIdx.x >> 6;
  const int wr = w >> 1, wc = w & 1, g = lane >> 4, t = lane & 15;
  if (z < 2) {
    unsigned short* O = (z == 0) ? Qb : Kb;
#pragma unroll
    for (int mi = 0; mi < 4; ++mi)
#pragma unroll
      for (int ni = 0; ni < 4; ++ni)
#pragma unroll
        for (int r = 0; r < 4; ++r) {
          int m = tm + wr * 64 + mi * 16 + g * 4 + r;
          int n = tn + wc * 64 + ni * 16 + t;
          int b = m >> 10, s = m & 1023, h = n >> 6, d = n & 63;
          O[((size_t)((b * 16 + h) * 1024 + s)) * 64 + d] = f2bf(acc[mi][ni][r]);
        }
  } else {
#pragma unroll
    for (int mi = 0; mi < 4; ++mi)
#pragma unroll
      for (int ni = 0; ni < 4; ++ni) {
        int m0 = tm + wr * 64 + mi * 16 + g * 4;
        int n = tn + wc * 64 + ni * 16 + t;
        int b = m0 >> 10, s0 = m0 & 1023, h = n >> 6, d = n & 63;
        ushort4v pk;
#pragma unroll
        for (int r = 0; r < 4; ++r) pk[r] = f2bf(acc[mi][ni][r]);
        *(ushort4v*)&Vt[((size_t)((b * 16 + h) * 64 + d) * 1024) + s0] = pk;
      }
  }
}

// ---------------- flash attention ----------------
// grid 512 (XCD-swizzled); block 512 = 8 waves; wave = 32 q-rows (256 q-rows/block).
// Per tile: QK^T of BOTH 32-key halves hoisted (s0,s1 back-to-back MFMA), then
// softmax0+PV0, softmax1+PV1. QK is m/l-independent so hoisting is bit-exact;
// per-q-row m->l->o update order unchanged vs R13.
__global__ __launch_bounds__(512) void k_attn(
    const unsigned short* __restrict__ Qb, const unsigned short* __restrict__ Kb,
    const unsigned short* __restrict__ Vt, const float* __restrict__ bt,
    unsigned short* __restrict__ ctx) {
  __shared__ alignas(16) unsigned short Ks[2][64 * 64];  // [key][d] swizzled, 8KB each
  __shared__ alignas(16) unsigned short Vs[2][64 * 64];  // [d][key] swizzled, 8KB each
  __shared__ alignas(16) float Lb[376];                  // bias, rel in [-186,189], log2e domain
  __shared__ float sred[8][32];

  const int wid = ((blockIdx.x & 7) << 6) | (blockIdx.x >> 3);  // XCD-local head grouping
  const int bh = wid >> 2, qb = wid & 3;
  const int h = bh & 15, b = bh >> 4;
  const int tid = threadIdx.x;
  const int lane = tid & 63, w = tid >> 6;
  const int ql = lane & 31, hi = lane >> 5;
  const int q0 = qb * 256 + w * 32;
  const int q = q0 + ql;

  for (int i = tid; i < 376; i += 512) Lb[i] = bt[(size_t)h * 2048 + 837 + i];  // 837 = 1023-186

  const unsigned short* Qp = Qb + (size_t)bh * SLEN * 64;
  const unsigned short* Kp = Kb + (size_t)bh * SLEN * 64;
  const unsigned short* Vp = Vt + (size_t)bh * 64 * SLEN;

  bf16x8 bq[4];
#pragma unroll
  for (int c = 0; c < 4; ++c)
    bq[c] = *(const bf16x8*)(Qp + (size_t)q * 64 + c * 16 + hi * 8);

  const f32x16 z16 = {0.f,0.f,0.f,0.f,0.f,0.f,0.f,0.f,0.f,0.f,0.f,0.f,0.f,0.f,0.f,0.f};
  f32x16 o0 = z16, o1 = z16;
  float m = -INFINITY, l = 0.f;

  auto stage = [&](int buf, int kbase) {
    int lb = w * 1024 + lane * 16;
    int row = lb >> 7;
    int lc = ((lb >> 4) & 7) ^ (row & 7);
    gload_lds16(Kp + (size_t)(kbase + row) * 64 + lc * 8, &Ks[buf][w * 512]);
    gload_lds16(Vp + (size_t)row * SLEN + kbase + lc * 8, &Vs[buf][w * 512]);
  };

  stage(0, 0);
  __syncthreads();
  const float cpos = Lb[186 + 91], cneg = Lb[186 - 91];

  int cur = 0;
#pragma unroll 1
  for (int kt = 0; kt < 16; ++kt) {
    const int kbase = kt * 64;
    if (kt != 15) stage(cur ^ 1, kbase + 64);

    const char* Kc = (const char*)Ks[cur];
    const char* Vc = (const char*)Vs[cur];

    // K frags for BOTH halves, then both QK^T MFMA clusters back-to-back.
    bf16x8 ak0[4], ak1[4];
#pragma unroll
    for (int c = 0; c < 4; ++c) {
      const int ph = ((c << 1) | hi) ^ (ql & 7);
      ak0[c] = *(const bf16x8*)(Kc + ql * 128 + ph * 16);
      ak1[c] = *(const bf16x8*)(Kc + (32 + ql) * 128 + ph * 16);
    }

    f32x16 s0 = z16, s1 = z16;
    __builtin_amdgcn_s_setprio(1);
#pragma unroll
    for (int c = 0; c < 4; ++c) s0 = MFMA32(ak0[c], bq[c], s0);
#pragma unroll
    for (int c = 0; c < 4; ++c) s1 = MFMA32(ak1[c], bq[c], s1);
    __builtin_amdgcn_s_setprio(0);

#pragma unroll
    for (int hh = 0; hh < 2; ++hh) {
      const int kb32 = kbase + hh * 32;
      f32x16 s = hh ? s1 : s0;

      // V frags for this half
      bf16x8 bv00, bv01, bv10, bv11;
      {
        const int p0 = ((hh << 2) | hi) ^ (ql & 7);
        const int p1 = ((hh << 2) | 2 | hi) ^ (ql & 7);
        bv00 = *(const bf16x8*)(Vc + ql * 128 + p0 * 16);
        bv01 = *(const bf16x8*)(Vc + (32 + ql) * 128 + p0 * 16);
        bv10 = *(const bf16x8*)(Vc + ql * 128 + p1 * 16);
        bv11 = *(const bf16x8*)(Vc + (32 + ql) * 128 + p1 * 16);
      }

      // bias in log2 domain
      const bool farp = (kb32 >= q0 + 122);
      const bool farn = (kb32 + 122 <= q0);
      if (farp || farn) {
        const float c = farp ? cpos : cneg;
#pragma unroll
        for (int r = 0; r < 16; ++r) s[r] = fmaf(s[r], LOG2E, c);
      } else {
        const int base = kb32 - q + 186 + hi * 4;
#pragma unroll
        for (int r = 0; r < 16; ++r)
          s[r] = fmaf(s[r], LOG2E, Lb[base + (r & 3) + 8 * (r >> 2)]);
      }

      // tile max: balanced tree (fmax exact) + one cross-half exchange
      float t0 = fmaxf(fmaxf(s[0], s[1]), fmaxf(s[2], s[3]));
      float t1 = fmaxf(fmaxf(s[4], s[5]), fmaxf(s[6], s[7]));
      float t2 = fmaxf(fmaxf(s[8], s[9]), fmaxf(s[10], s[11]));
      float t3 = fmaxf(fmaxf(s[12], s[13]), fmaxf(s[14], s[15]));
      float vm = fmaxf(fmaxf(t0, t1), fmaxf(t2, t3));
      vm = fmaxf(vm, __shfl_xor(vm, 32));

      // defer-max rescale (THR=8 in log2 domain; algebraically exact)
      if (__any(vm > m + 8.0f)) {
        const float mn = fmaxf(m, vm);
        const float sc = fast_exp2(m - mn);
        m = mn;
        l *= sc;
        sred[w][ql] = sc;
        __builtin_amdgcn_wave_barrier();
#pragma unroll
        for (int r = 0; r < 16; ++r) {
          const float sr = sred[w][(r & 3) + 8 * (r >> 2) + hi * 4];
          o0[r] *= sr; o1[r] *= sr;
        }
        __builtin_amdgcn_wave_barrier();
      }

      // P = exp2(s - m), row sum (serial order preserved)
      float p[16];
      float ls = 0.f;
#pragma unroll
      for (int r = 0; r < 16; ++r) { p[r] = fast_exp2(s[r] - m); ls += p[r]; }
      l += ls + __shfl_xor(ls, 32);

      // pack P -> PV A-frags (keys contiguous per lane via cross-half exchange)
      unsigned int wv[8], xv[8];
#pragma unroll
      for (int i = 0; i < 8; ++i) wv[i] = cvt_pk_bf16(p[2 * i], p[2 * i + 1]);
#pragma unroll
      for (int i = 0; i < 8; ++i) xv[i] = __shfl_xor(wv[i], 32);
      union { unsigned int u[4]; bf16x8 v; } pa0, pa1;
      pa0.u[0] = hi ? xv[2] : wv[0];
      pa0.u[1] = hi ? xv[3] : wv[1];
      pa0.u[2] = hi ? wv[2] : xv[0];
      pa0.u[3] = hi ? wv[3] : xv[1];
      pa1.u[0] = hi ? xv[6] : wv[4];
      pa1.u[1] = hi ? xv[7] : wv[5];
      pa1.u[2] = hi ? wv[6] : xv[4];
      pa1.u[3] = hi ? wv[7] : xv[5];

      // PV: O[q][d] += P[q][k] V[k][d]
      __builtin_amdgcn_s_setprio(1);
      o0 = MFMA32(pa0.v, bv00, o0);
      o0 = MFMA32(pa1.v, bv10, o0);
      o1 = MFMA32(pa0.v, bv01, o1);
      o1 = MFMA32(pa1.v, bv11, o1);
      __builtin_amdgcn_s_setprio(0);
    }

    __syncthreads();
    cur ^= 1;
  }

  // finalize
  const float inv = 1.0f / l;
  sred[w][ql] = inv;
  __builtin_amdgcn_wave_barrier();
#pragma unroll
  for (int r = 0; r < 16; ++r) {
    const float ir = sred[w][(r & 3) + 8 * (r >> 2) + hi * 4];
    const int qq = q0 + (r & 3) + 8 * (r >> 2) + hi * 4;
    const size_t base = ((size_t)(b * 1024 + qq)) * 1024 + h * 64 + ql;
    ctx[base] = f2bf(o0[r] * ir);
    ctx[base + 32] = f2bf(o1[r] * ir);
  }
}

// ---------------- output projection: out = ctx @ wo (f32 out) ----------------
__global__ __launch_bounds__(256) void k_gemm_out(
    const unsigned short* __restrict__ Cb, const unsigned short* __restrict__ Wot,
    float* __restrict__ out) {
  __shared__ alignas(16) unsigned short As[2 * 128 * 64];
  __shared__ alignas(16) unsigned short Bs[2 * 128 * 64];
  const int wid = (blockIdx.x & 7) * 64 + (blockIdx.x >> 3);  // XCD swizzle
  int tm = (wid >> 3) * 128, tn = (wid & 7) * 128;
  f32x4 acc[4][4];
  gemm_tile_lds(Cb, Wot, DMODEL, tm, tn, As, Bs, acc);

  const int lane = threadIdx.x & 63, w = threadIdx.x >> 6;
  const int wr = w >> 1, wc = w & 1, g = lane >> 4, t = lane & 15;
#pragma unroll
  for (int mi = 0; mi < 4; ++mi)
#pragma unroll
    for (int ni = 0; ni < 4; ++ni)
#pragma unroll
      for (int r = 0; r < 4; ++r) {
        int m = tm + wr * 64 + mi * 16 + g * 4 + r;
        int n = tn + wc * 64 + ni * 16 + t;
        out[(size_t)m * DMODEL + n] = acc[mi][ni][r];
      }
}

extern "C" void kernel_launch(void* const* d_in, const int* in_sizes, int n_in,
                              void* d_out, int out_size, void* d_ws, size_t ws_size,
                              hipStream_t stream) {
  const float* hs = (const float*)d_in[0];
  const float* wq = (const float*)d_in[1];
  const float* wk = (const float*)d_in[2];
  const float* wv = (const float*)d_in[3];
  const float* wo = (const float*)d_in[4];
  const float* rb = (const float*)d_in[5];

  char* ws = (char*)d_ws;
  unsigned short* Xb  = (unsigned short*)(ws + 0);          // 16 MB
  unsigned short* Wqt = (unsigned short*)(ws + 16777216);   // 2 MB
  unsigned short* Wkt = (unsigned short*)(ws + 18874368);
  unsigned short* Wvt = (unsigned short*)(ws + 20971520);
  unsigned short* Wot = (unsigned short*)(ws + 23068672);
  unsigned short* Qb  = (unsigned short*)(ws + 25165824);   // 16 MB
  unsigned short* Kb  = (unsigned short*)(ws + 41943040);   // 16 MB
  unsigned short* Vt  = (unsigned short*)(ws + 58720256);   // 16 MB
  unsigned short* Cb  = (unsigned short*)(ws + 75497472);   // 16 MB
  float* bt           = (float*)(ws + 92274688);            // 128 KB

  k_prep<<<8320, 256, 0, stream>>>(hs, Xb, wq, wk, wv, wo, Wqt, Wkt, Wvt, Wot, rb, bt);
  k_gemm_qkv<<<dim3(512, 1, 3), 256, 0, stream>>>(Xb, Wqt, Wkt, Wvt, Qb, Kb, Vt);
  k_attn<<<512, 512, 0, stream>>>(Qb, Kb, Vt, bt, Cb);
  k_gemm_out<<<512, 256, 0, stream>>>(Cb, Wot, (float*)d_out);
}

// Round 15
// 166.101 us; speedup vs baseline: 1.0172x; 1.0172x over previous
//
#include <hip/hip_runtime.h>
#include <stdint.h>

typedef __attribute__((ext_vector_type(8))) short bf16x8;
typedef __attribute__((ext_vector_type(4))) float f32x4;
typedef __attribute__((ext_vector_type(16))) float f32x16;
typedef __attribute__((ext_vector_type(8))) unsigned short ushort8;
typedef __attribute__((ext_vector_type(4))) unsigned short ushort4v;

#define MFMA16(a, b, c) __builtin_amdgcn_mfma_f32_16x16x32_bf16((a), (b), (c), 0, 0, 0)
#define MFMA32(a, b, c) __builtin_amdgcn_mfma_f32_32x32x16_bf16((a), (b), (c), 0, 0, 0)

// B=8, S=1024, D=1024, H=16, DK=64
#define SLEN 1024
#define NHEAD 16
#define HDIM 64
#define DMODEL 1024
#define NROWS 8192  // B*S
#define LOG2E 1.44269504088896340736f

__device__ __forceinline__ unsigned short f2bf(float f) {
  unsigned int u = __float_as_uint(f);
  u += 0x7FFFu + ((u >> 16) & 1u);   // RNE
  return (unsigned short)(u >> 16);
}

__device__ __forceinline__ float fast_exp2(float x) {
#if __has_builtin(__builtin_amdgcn_exp2f)
  return __builtin_amdgcn_exp2f(x);
#else
  float r; asm("v_exp_f32 %0, %1" : "=v"(r) : "v"(x)); return r;
#endif
}

__device__ __forceinline__ unsigned int cvt_pk_bf16(float lo, float hi) {
  unsigned int r;
  asm("v_cvt_pk_bf16_f32 %0, %1, %2" : "=v"(r) : "v"(lo), "v"(hi));
  return r;
}

// v_permlane32_swap (VALU): returns pair; {ret0, ret1} = {both-low-rows, both-high-rows}
// under S1 (vdst.hi<->src.lo). xhalf_* combine BOTH returns commutatively -> correct
// under ANY swap-semantics/return-order (verified invariance; R11 post-mortem).
__device__ __forceinline__ float xhalf_max(float x) {
  unsigned int u = __float_as_uint(x);
  auto r = __builtin_amdgcn_permlane32_swap(u, u, false, false);
  return fmaxf(__uint_as_float(r[0]), __uint_as_float(r[1]));
}
__device__ __forceinline__ float xhalf_sum(float x) {
  unsigned int u = __float_as_uint(x);
  auto r = __builtin_amdgcn_permlane32_swap(u, u, false, false);
  return __uint_as_float(r[0]) + __uint_as_float(r[1]);
}

// async global->LDS, 16B per lane; LDS dest = wave-uniform base + lane*16 (HW).
__device__ __forceinline__ void gload_lds16(const void* g, void* l) {
  __builtin_amdgcn_global_load_lds(
      (const __attribute__((address_space(1))) void*)g,
      (__attribute__((address_space(3))) void*)l, 16, 0, 0);
}

// ---------------- fused prep: convert X, transpose weights, bias table ----------------
__global__ __launch_bounds__(256) void k_prep(
    const float* __restrict__ x, unsigned short* __restrict__ xb,
    const float* __restrict__ w0, const float* __restrict__ w1,
    const float* __restrict__ w2, const float* __restrict__ w3,
    unsigned short* __restrict__ o0, unsigned short* __restrict__ o1,
    unsigned short* __restrict__ o2, unsigned short* __restrict__ o3,
    const float* __restrict__ rel_bias, float* __restrict__ bt) {
  const int bi = blockIdx.x;
  const int tid = threadIdx.x;
  if (bi < 4096) {
    int idx = (bi * 256 + tid) * 8;
    float4 a = *(const float4*)(x + idx);
    float4 b = *(const float4*)(x + idx + 4);
    ushort8 o;
    o[0] = f2bf(a.x); o[1] = f2bf(a.y); o[2] = f2bf(a.z); o[3] = f2bf(a.w);
    o[4] = f2bf(b.x); o[5] = f2bf(b.y); o[6] = f2bf(b.z); o[7] = f2bf(b.w);
    *(ushort8*)(xb + idx) = o;
  } else if (bi < 8192) {
    const int t = bi - 4096;
    const int z = t >> 10;
    const float* w = (z == 0) ? w0 : (z == 1) ? w1 : (z == 2) ? w2 : w3;
    unsigned short* o = (z == 0) ? o0 : (z == 1) ? o1 : (z == 2) ? o2 : o3;
    __shared__ unsigned short tile[32][33];
    const int bx = t & 31, by = (t & 1023) >> 5;
#pragma unroll
    for (int p = 0; p < 4; ++p) {
      int idx = tid + p * 256;
      int r = idx >> 5, c = idx & 31;
      tile[r][c] = f2bf(w[(size_t)(by * 32 + r) * DMODEL + bx * 32 + c]);
    }
    __syncthreads();
#pragma unroll
    for (int p = 0; p < 4; ++p) {
      int idx = tid + p * 256;
      int r = idx >> 5, c = idx & 31;
      o[(size_t)(bx * 32 + r) * DMODEL + by * 32 + c] = tile[c][r];
    }
  } else {
    int i = (bi - 8192) * 256 + tid;
    if (i >= NHEAD * 2047) return;
    int h = i / 2047, rdx = i % 2047;
    int rel = rdx - 1023;
    int rb = (rel > 0) ? 16 : 0;
    int rp = (rel < 0) ? -rel : rel;
    int bucket;
    if (rp < 8) {
      bucket = rb + rp;
    } else {
      int large;
      if (rp >= 91) {
        large = 15;
      } else {
        int nb = 31 - __clz(rp);
        long long sq = (long long)rp * rp;
        int f2 = 2 * nb + ((sq >= (1LL << (2 * nb + 1))) ? 1 : 0);
        large = 8 + (f2 - 6);
        if (large > 15) large = 15;
      }
      bucket = rb + large;
    }
    bt[h * 2048 + rdx] = rel_bias[bucket * 16 + h] * LOG2E;
  }
}

// ---------------- 2-phase GEMM core, BK=64, XOR-swizzled LDS (R10-verified) ----------------
__device__ __forceinline__ void gemm_tile_lds(const unsigned short* __restrict__ A,
                                              const unsigned short* __restrict__ Bt,
                                              int K, int tm, int tn,
                                              unsigned short* As, unsigned short* Bs,
                                              f32x4 acc[4][4]) {
  const int tid = threadIdx.x;
  const int lane = tid & 63;
  const int w = tid >> 6;
  const int wr = w >> 1, wc = w & 1;
  const int g = lane >> 4, t = lane & 15;
  const int NKT = K >> 6;   // BK=64

  auto stageT = [&](int bufo, int ko) {
#pragma unroll
    for (int j = 0; j < 4; ++j) {
      const int r = w * 32 + j * 8 + (lane >> 3);
      const int lc = (lane & 7) ^ (r & 7);
      gload_lds16(A + (size_t)(tm + r) * K + ko + lc * 8, As + bufo + (w * 4 + j) * 512);
      gload_lds16(Bt + (size_t)(tn + r) * K + ko + lc * 8, Bs + bufo + (w * 4 + j) * 512);
    }
  };

  f32x4 z = {0.f, 0.f, 0.f, 0.f};
#pragma unroll
  for (int mi = 0; mi < 4; ++mi)
#pragma unroll
    for (int ni = 0; ni < 4; ++ni) acc[mi][ni] = z;

  stageT(0, 0);
  __syncthreads();

#pragma unroll 1
  for (int kt = 0; kt < NKT; ++kt) {
    const int cur = (kt & 1) * 8192;
    if (kt + 1 < NKT) stageT(cur ^ 8192, (kt + 1) * 64);

    bf16x8 af[2][4], bfr[2][4];
#pragma unroll
    for (int kk = 0; kk < 2; ++kk)
#pragma unroll
      for (int mi = 0; mi < 4; ++mi) {
        const int ra = wr * 64 + mi * 16 + t;
        const int pa = ((kk << 2) | g) ^ (ra & 7);
        af[kk][mi] = *(const bf16x8*)&As[cur + ra * 64 + pa * 8];
      }
#pragma unroll
    for (int kk = 0; kk < 2; ++kk)
#pragma unroll
      for (int ni = 0; ni < 4; ++ni) {
        const int rb = wc * 64 + ni * 16 + t;
        const int pb = ((kk << 2) | g) ^ (rb & 7);
        bfr[kk][ni] = *(const bf16x8*)&Bs[cur + rb * 64 + pb * 8];
      }
#pragma unroll
    for (int kk = 0; kk < 2; ++kk)
#pragma unroll
      for (int mi = 0; mi < 4; ++mi)
#pragma unroll
        for (int ni = 0; ni < 4; ++ni)
          acc[mi][ni] = MFMA16(af[kk][mi], bfr[kk][ni], acc[mi][ni]);

    __syncthreads();
  }
}

// ---------------- QKV projection ----------------
__global__ __launch_bounds__(256) void k_gemm_qkv(
    const unsigned short* __restrict__ Xb,
    const unsigned short* __restrict__ Wqt, const unsigned short* __restrict__ Wkt,
    const unsigned short* __restrict__ Wvt,
    unsigned short* __restrict__ Qb, unsigned short* __restrict__ Kb,
    unsigned short* __restrict__ Vt) {
  __shared__ alignas(16) unsigned short As[2 * 128 * 64];
  __shared__ alignas(16) unsigned short Bs[2 * 128 * 64];
  int z = blockIdx.z;
  const unsigned short* Bt = (z == 0) ? Wqt : (z == 1) ? Wkt : Wvt;
  const int wid = (blockIdx.x & 7) * 64 + (blockIdx.x >> 3);
  int tm = (wid >> 3) * 128, tn = (wid & 7) * 128;
  f32x4 acc[4][4];
  gemm_tile_lds(Xb, Bt, DMODEL, tm, tn, As, Bs, acc);

  const int lane = threadIdx.x & 63, w = threadIdx.x >> 6;
  const int wr = w >> 1, wc = w & 1, g = lane >> 4, t = lane & 15;
  if (z < 2) {
    unsigned short* O = (z == 0) ? Qb : Kb;
#pragma unroll
    for (int mi = 0; mi < 4; ++mi)
#pragma unroll
      for (int ni = 0; ni < 4; ++ni)
#pragma unroll
        for (int r = 0; r < 4; ++r) {
          int m = tm + wr * 64 + mi * 16 + g * 4 + r;
          int n = tn + wc * 64 + ni * 16 + t;
          int b = m >> 10, s = m & 1023, h = n >> 6, d = n & 63;
          O[((size_t)((b * 16 + h) * 1024 + s)) * 64 + d] = f2bf(acc[mi][ni][r]);
        }
  } else {
#pragma unroll
    for (int mi = 0; mi < 4; ++mi)
#pragma unroll
      for (int ni = 0; ni < 4; ++ni) {
        int m0 = tm + wr * 64 + mi * 16 + g * 4;
        int n = tn + wc * 64 + ni * 16 + t;
        int b = m0 >> 10, s0 = m0 & 1023, h = n >> 6, d = n & 63;
        ushort4v pk;
#pragma unroll
        for (int r = 0; r < 4; ++r) pk[r] = f2bf(acc[mi][ni][r]);
        *(ushort4v*)&Vt[((size_t)((b * 16 + h) * 64 + d) * 1024) + s0] = pk;
      }
  }
}

// ---------------- flash attention (R13 structure; cross-lane via permlane32_swap) ----------------
// grid 512 (XCD-swizzled); block 512 = 8 waves; wave = 32 q-rows (256 q-rows/block).
__global__ __launch_bounds__(512) void k_attn(
    const unsigned short* __restrict__ Qb, const unsigned short* __restrict__ Kb,
    const unsigned short* __restrict__ Vt, const float* __restrict__ bt,
    unsigned short* __restrict__ ctx) {
  __shared__ alignas(16) unsigned short Ks[2][64 * 64];  // [key][d] swizzled, 8KB each
  __shared__ alignas(16) unsigned short Vs[2][64 * 64];  // [d][key] swizzled, 8KB each
  __shared__ alignas(16) float Lb[376];                  // bias, rel in [-186,189], log2e domain
  __shared__ float sred[8][32];

  const int wid = ((blockIdx.x & 7) << 6) | (blockIdx.x >> 3);  // XCD-local head grouping
  const int bh = wid >> 2, qb = wid & 3;
  const int h = bh & 15, b = bh >> 4;
  const int tid = threadIdx.x;
  const int lane = tid & 63, w = tid >> 6;
  const int ql = lane & 31, hi = lane >> 5;
  const int q0 = qb * 256 + w * 32;
  const int q = q0 + ql;

  for (int i = tid; i < 376; i += 512) Lb[i] = bt[(size_t)h * 2048 + 837 + i];  // 837 = 1023-186

  const unsigned short* Qp = Qb + (size_t)bh * SLEN * 64;
  const unsigned short* Kp = Kb + (size_t)bh * SLEN * 64;
  const unsigned short* Vp = Vt + (size_t)bh * 64 * SLEN;

  bf16x8 bq[4];
#pragma unroll
  for (int c = 0; c < 4; ++c)
    bq[c] = *(const bf16x8*)(Qp + (size_t)q * 64 + c * 16 + hi * 8);

  const f32x16 z16 = {0.f,0.f,0.f,0.f,0.f,0.f,0.f,0.f,0.f,0.f,0.f,0.f,0.f,0.f,0.f,0.f};
  f32x16 o0 = z16, o1 = z16;
  float m = -INFINITY, l = 0.f;

  auto stage = [&](int buf, int kbase) {
    int lb = w * 1024 + lane * 16;
    int row = lb >> 7;
    int lc = ((lb >> 4) & 7) ^ (row & 7);
    gload_lds16(Kp + (size_t)(kbase + row) * 64 + lc * 8, &Ks[buf][w * 512]);
    gload_lds16(Vp + (size_t)row * SLEN + kbase + lc * 8, &Vs[buf][w * 512]);
  };

  stage(0, 0);
  __syncthreads();
  const float cpos = Lb[186 + 91], cneg = Lb[186 - 91];

  int cur = 0;
#pragma unroll 1
  for (int kt = 0; kt < 16; ++kt) {
    const int kbase = kt * 64;
    if (kt != 15) stage(cur ^ 1, kbase + 64);

    const char* Kc = (const char*)Ks[cur];
    const char* Vc = (const char*)Vs[cur];

#pragma unroll
    for (int hh = 0; hh < 2; ++hh) {
      const int kb32 = kbase + hh * 32;

      bf16x8 ak[4];
#pragma unroll
      for (int c = 0; c < 4; ++c) {
        const int ph = ((c << 1) | hi) ^ (ql & 7);
        ak[c] = *(const bf16x8*)(Kc + (hh * 32 + ql) * 128 + ph * 16);
      }

      bf16x8 bv00, bv01, bv10, bv11;
      {
        const int p0 = ((hh << 2) | hi) ^ (ql & 7);
        const int p1 = ((hh << 2) | 2 | hi) ^ (ql & 7);
        bv00 = *(const bf16x8*)(Vc + ql * 128 + p0 * 16);
        bv01 = *(const bf16x8*)(Vc + (32 + ql) * 128 + p0 * 16);
        bv10 = *(const bf16x8*)(Vc + ql * 128 + p1 * 16);
        bv11 = *(const bf16x8*)(Vc + (32 + ql) * 128 + p1 * 16);
      }

      // QK^T: S[k][q]
      f32x16 s = z16;
      __builtin_amdgcn_s_setprio(1);
#pragma unroll
      for (int c = 0; c < 4; ++c) s = MFMA32(ak[c], bq[c], s);
      __builtin_amdgcn_s_setprio(0);

      // bias in log2 domain
      const bool farp = (kb32 >= q0 + 122);
      const bool farn = (kb32 + 122 <= q0);
      if (farp || farn) {
        const float c = farp ? cpos : cneg;
#pragma unroll
        for (int r = 0; r < 16; ++r) s[r] = fmaf(s[r], LOG2E, c);
      } else {
        const int base = kb32 - q + 186 + hi * 4;
#pragma unroll
        for (int r = 0; r < 16; ++r)
          s[r] = fmaf(s[r], LOG2E, Lb[base + (r & 3) + 8 * (r >> 2)]);
      }

      // tile max: balanced tree (fmax exact) + cross-half via permlane (semantics-invariant)
      float t0 = fmaxf(fmaxf(s[0], s[1]), fmaxf(s[2], s[3]));
      float t1 = fmaxf(fmaxf(s[4], s[5]), fmaxf(s[6], s[7]));
      float t2 = fmaxf(fmaxf(s[8], s[9]), fmaxf(s[10], s[11]));
      float t3 = fmaxf(fmaxf(s[12], s[13]), fmaxf(s[14], s[15]));
      float vm = xhalf_max(fmaxf(fmaxf(t0, t1), fmaxf(t2, t3)));

      // defer-max rescale (THR=8 in log2 domain; algebraically exact)
      if (__any(vm > m + 8.0f)) {
        const float mn = fmaxf(m, vm);
        const float sc = fast_exp2(m - mn);
        m = mn;
        l *= sc;
        sred[w][ql] = sc;
        __builtin_amdgcn_wave_barrier();
#pragma unroll
        for (int r = 0; r < 16; ++r) {
          const float sr = sred[w][(r & 3) + 8 * (r >> 2) + hi * 4];
          o0[r] *= sr; o1[r] *= sr;
        }
        __builtin_amdgcn_wave_barrier();
      }

      // P = exp2(s - m), row sum (serial order preserved); cross-half sum via permlane
      float p[16];
      float ls = 0.f;
#pragma unroll
      for (int r = 0; r < 16; ++r) { p[r] = fast_exp2(s[r] - m); ls += p[r]; }
      l += xhalf_sum(ls);

      // pack P -> PV A-frags via permlane32_swap, S1 mapping:
      // swap(wv[a], wv[a+2]) -> ret0 = {wv[a].lo | wv[a+2].lo} = pa.u[a],
      //                         ret1 = {wv[a].hi | wv[a+2].hi} = pa.u[a+2].
      // (S2-normal mapping was refuted by R11's failure; returns follow operand order.)
      unsigned int wv[8];
#pragma unroll
      for (int i = 0; i < 8; ++i) wv[i] = cvt_pk_bf16(p[2 * i], p[2 * i + 1]);
      union { unsigned int u[4]; bf16x8 v; } pa0, pa1;
      {
        auto r02 = __builtin_amdgcn_permlane32_swap(wv[0], wv[2], false, false);
        pa0.u[0] = r02[0]; pa0.u[2] = r02[1];
        auto r13 = __builtin_amdgcn_permlane32_swap(wv[1], wv[3], false, false);
        pa0.u[1] = r13[0]; pa0.u[3] = r13[1];
        auto r46 = __builtin_amdgcn_permlane32_swap(wv[4], wv[6], false, false);
        pa1.u[0] = r46[0]; pa1.u[2] = r46[1];
        auto r57 = __builtin_amdgcn_permlane32_swap(wv[5], wv[7], false, false);
        pa1.u[1] = r57[0]; pa1.u[3] = r57[1];
      }

      // PV: O[q][d] += P[q][k] V[k][d]
      __builtin_amdgcn_s_setprio(1);
      o0 = MFMA32(pa0.v, bv00, o0);
      o0 = MFMA32(pa1.v, bv10, o0);
      o1 = MFMA32(pa0.v, bv01, o1);
      o1 = MFMA32(pa1.v, bv11, o1);
      __builtin_amdgcn_s_setprio(0);
    }

    __syncthreads();
    cur ^= 1;
  }

  // finalize
  const float inv = 1.0f / l;
  sred[w][ql] = inv;
  __builtin_amdgcn_wave_barrier();
#pragma unroll
  for (int r = 0; r < 16; ++r) {
    const float ir = sred[w][(r & 3) + 8 * (r >> 2) + hi * 4];
    const int qq = q0 + (r & 3) + 8 * (r >> 2) + hi * 4;
    const size_t base = ((size_t)(b * 1024 + qq)) * 1024 + h * 64 + ql;
    ctx[base] = f2bf(o0[r] * ir);
    ctx[base + 32] = f2bf(o1[r] * ir);
  }
}

// ---------------- output projection: out = ctx @ wo (f32 out) ----------------
__global__ __launch_bounds__(256) void k_gemm_out(
    const unsigned short* __restrict__ Cb, const unsigned short* __restrict__ Wot,
    float* __restrict__ out) {
  __shared__ alignas(16) unsigned short As[2 * 128 * 64];
  __shared__ alignas(16) unsigned short Bs[2 * 128 * 64];
  const int wid = (blockIdx.x & 7) * 64 + (blockIdx.x >> 3);  // XCD swizzle
  int tm = (wid >> 3) * 128, tn = (wid & 7) * 128;
  f32x4 acc[4][4];
  gemm_tile_lds(Cb, Wot, DMODEL, tm, tn, As, Bs, acc);

  const int lane = threadIdx.x & 63, w = threadIdx.x >> 6;
  const int wr = w >> 1, wc = w & 1, g = lane >> 4, t = lane & 15;
#pragma unroll
  for (int mi = 0; mi < 4; ++mi)
#pragma unroll
    for (int ni = 0; ni < 4; ++ni)
#pragma unroll
      for (int r = 0; r < 4; ++r) {
        int m = tm + wr * 64 + mi * 16 + g * 4 + r;
        int n = tn + wc * 64 + ni * 16 + t;
        out[(size_t)m * DMODEL + n] = acc[mi][ni][r];
      }
}

extern "C" void kernel_launch(void* const* d_in, const int* in_sizes, int n_in,
                              void* d_out, int out_size, void* d_ws, size_t ws_size,
                              hipStream_t stream) {
  const float* hs = (const float*)d_in[0];
  const float* wq = (const float*)d_in[1];
  const float* wk = (const float*)d_in[2];
  const float* wv = (const float*)d_in[3];
  const float* wo = (const float*)d_in[4];
  const float* rb = (const float*)d_in[5];

  char* ws = (char*)d_ws;
  unsigned short* Xb  = (unsigned short*)(ws + 0);          // 16 MB
  unsigned short* Wqt = (unsigned short*)(ws + 16777216);   // 2 MB
  unsigned short* Wkt = (unsigned short*)(ws + 18874368);
  unsigned short* Wvt = (unsigned short*)(ws + 20971520);
  unsigned short* Wot = (unsigned short*)(ws + 23068672);
  unsigned short* Qb  = (unsigned short*)(ws + 25165824);   // 16 MB
  unsigned short* Kb  = (unsigned short*)(ws + 41943040);   // 16 MB
  unsigned short* Vt  = (unsigned short*)(ws + 58720256);   // 16 MB
  unsigned short* Cb  = (unsigned short*)(ws + 75497472);   // 16 MB
  float* bt           = (float*)(ws + 92274688);            // 128 KB

  k_prep<<<8320, 256, 0, stream>>>(hs, Xb, wq, wk, wv, wo, Wqt, Wkt, Wvt, Wot, rb, bt);
  k_gemm_qkv<<<dim3(512, 1, 3), 256, 0, stream>>>(Xb, Wqt, Wkt, Wvt, Qb, Kb, Vt);
  k_attn<<<512, 512, 0, stream>>>(Qb, Kb, Vt, bt, Cb);
  k_gemm_out<<<512, 256, 0, stream>>>(Cb, Wot, (float*)d_out);
}

// Round 16
// 159.499 us; speedup vs baseline: 1.0593x; 1.0414x over previous
//
#include <hip/hip_runtime.h>
#include <stdint.h>

typedef __attribute__((ext_vector_type(8))) short bf16x8;
typedef __attribute__((ext_vector_type(4))) float f32x4;
typedef __attribute__((ext_vector_type(16))) float f32x16;
typedef __attribute__((ext_vector_type(8))) unsigned short ushort8;
typedef __attribute__((ext_vector_type(4))) unsigned short ushort4v;

#define MFMA16(a, b, c) __builtin_amdgcn_mfma_f32_16x16x32_bf16((a), (b), (c), 0, 0, 0)
#define MFMA32(a, b, c) __builtin_amdgcn_mfma_f32_32x32x16_bf16((a), (b), (c), 0, 0, 0)

// B=8, S=1024, D=1024, H=16, DK=64
#define SLEN 1024
#define NHEAD 16
#define HDIM 64
#define DMODEL 1024
#define NROWS 8192  // B*S
#define LOG2E 1.44269504088896340736f

__device__ __forceinline__ unsigned short f2bf(float f) {
  unsigned int u = __float_as_uint(f);
  u += 0x7FFFu + ((u >> 16) & 1u);   // RNE
  return (unsigned short)(u >> 16);
}

__device__ __forceinline__ float fast_exp2(float x) {
#if __has_builtin(__builtin_amdgcn_exp2f)
  return __builtin_amdgcn_exp2f(x);
#else
  float r; asm("v_exp_f32 %0, %1" : "=v"(r) : "v"(x)); return r;
#endif
}

__device__ __forceinline__ unsigned int cvt_pk_bf16(float lo, float hi) {
  unsigned int r;
  asm("v_cvt_pk_bf16_f32 %0, %1, %2" : "=v"(r) : "v"(lo), "v"(hi));
  return r;
}

// v_permlane32_swap (VALU): S1 semantics, returns follow operand order
// ({ret0, ret1} = {both-low-rows, both-high-rows}) — verified R15 (bit-exact pass).
// xhalf_* combine BOTH returns commutatively -> semantics-invariant.
__device__ __forceinline__ float xhalf_max(float x) {
  unsigned int u = __float_as_uint(x);
  auto r = __builtin_amdgcn_permlane32_swap(u, u, false, false);
  return fmaxf(__uint_as_float(r[0]), __uint_as_float(r[1]));
}
__device__ __forceinline__ float xhalf_sum(float x) {
  unsigned int u = __float_as_uint(x);
  auto r = __builtin_amdgcn_permlane32_swap(u, u, false, false);
  return __uint_as_float(r[0]) + __uint_as_float(r[1]);
}

// async global->LDS, 16B per lane; LDS dest = wave-uniform base + lane*16 (HW).
__device__ __forceinline__ void gload_lds16(const void* g, void* l) {
  __builtin_amdgcn_global_load_lds(
      (const __attribute__((address_space(1))) void*)g,
      (__attribute__((address_space(3))) void*)l, 16, 0, 0);
}

// ---------------- fused prep: convert X, transpose weights, bias table ----------------
__global__ __launch_bounds__(256) void k_prep(
    const float* __restrict__ x, unsigned short* __restrict__ xb,
    const float* __restrict__ w0, const float* __restrict__ w1,
    const float* __restrict__ w2, const float* __restrict__ w3,
    unsigned short* __restrict__ o0, unsigned short* __restrict__ o1,
    unsigned short* __restrict__ o2, unsigned short* __restrict__ o3,
    const float* __restrict__ rel_bias, float* __restrict__ bt) {
  const int bi = blockIdx.x;
  const int tid = threadIdx.x;
  if (bi < 4096) {
    int idx = (bi * 256 + tid) * 8;
    float4 a = *(const float4*)(x + idx);
    float4 b = *(const float4*)(x + idx + 4);
    ushort8 o;
    o[0] = f2bf(a.x); o[1] = f2bf(a.y); o[2] = f2bf(a.z); o[3] = f2bf(a.w);
    o[4] = f2bf(b.x); o[5] = f2bf(b.y); o[6] = f2bf(b.z); o[7] = f2bf(b.w);
    *(ushort8*)(xb + idx) = o;
  } else if (bi < 8192) {
    const int t = bi - 4096;
    const int z = t >> 10;
    const float* w = (z == 0) ? w0 : (z == 1) ? w1 : (z == 2) ? w2 : w3;
    unsigned short* o = (z == 0) ? o0 : (z == 1) ? o1 : (z == 2) ? o2 : o3;
    __shared__ unsigned short tile[32][33];
    const int bx = t & 31, by = (t & 1023) >> 5;
#pragma unroll
    for (int p = 0; p < 4; ++p) {
      int idx = tid + p * 256;
      int r = idx >> 5, c = idx & 31;
      tile[r][c] = f2bf(w[(size_t)(by * 32 + r) * DMODEL + bx * 32 + c]);
    }
    __syncthreads();
#pragma unroll
    for (int p = 0; p < 4; ++p) {
      int idx = tid + p * 256;
      int r = idx >> 5, c = idx & 31;
      o[(size_t)(bx * 32 + r) * DMODEL + by * 32 + c] = tile[c][r];
    }
  } else {
    int i = (bi - 8192) * 256 + tid;
    if (i >= NHEAD * 2047) return;
    int h = i / 2047, rdx = i % 2047;
    int rel = rdx - 1023;
    int rb = (rel > 0) ? 16 : 0;
    int rp = (rel < 0) ? -rel : rel;
    int bucket;
    if (rp < 8) {
      bucket = rb + rp;
    } else {
      int large;
      if (rp >= 91) {
        large = 15;
      } else {
        int nb = 31 - __clz(rp);
        long long sq = (long long)rp * rp;
        int f2 = 2 * nb + ((sq >= (1LL << (2 * nb + 1))) ? 1 : 0);
        large = 8 + (f2 - 6);
        if (large > 15) large = 15;
      }
      bucket = rb + large;
    }
    bt[h * 2048 + rdx] = rel_bias[bucket * 16 + h] * LOG2E;
  }
}

// ---------------- 2-phase GEMM core, BK=64, XOR-swizzled LDS (R10-verified) ----------------
__device__ __forceinline__ void gemm_tile_lds(const unsigned short* __restrict__ A,
                                              const unsigned short* __restrict__ Bt,
                                              int K, int tm, int tn,
                                              unsigned short* As, unsigned short* Bs,
                                              f32x4 acc[4][4]) {
  const int tid = threadIdx.x;
  const int lane = tid & 63;
  const int w = tid >> 6;
  const int wr = w >> 1, wc = w & 1;
  const int g = lane >> 4, t = lane & 15;
  const int NKT = K >> 6;   // BK=64

  auto stageT = [&](int bufo, int ko) {
#pragma unroll
    for (int j = 0; j < 4; ++j) {
      const int r = w * 32 + j * 8 + (lane >> 3);
      const int lc = (lane & 7) ^ (r & 7);
      gload_lds16(A + (size_t)(tm + r) * K + ko + lc * 8, As + bufo + (w * 4 + j) * 512);
      gload_lds16(Bt + (size_t)(tn + r) * K + ko + lc * 8, Bs + bufo + (w * 4 + j) * 512);
    }
  };

  f32x4 z = {0.f, 0.f, 0.f, 0.f};
#pragma unroll
  for (int mi = 0; mi < 4; ++mi)
#pragma unroll
    for (int ni = 0; ni < 4; ++ni) acc[mi][ni] = z;

  stageT(0, 0);
  __syncthreads();

#pragma unroll 1
  for (int kt = 0; kt < NKT; ++kt) {
    const int cur = (kt & 1) * 8192;
    if (kt + 1 < NKT) stageT(cur ^ 8192, (kt + 1) * 64);

    bf16x8 af[2][4], bfr[2][4];
#pragma unroll
    for (int kk = 0; kk < 2; ++kk)
#pragma unroll
      for (int mi = 0; mi < 4; ++mi) {
        const int ra = wr * 64 + mi * 16 + t;
        const int pa = ((kk << 2) | g) ^ (ra & 7);
        af[kk][mi] = *(const bf16x8*)&As[cur + ra * 64 + pa * 8];
      }
#pragma unroll
    for (int kk = 0; kk < 2; ++kk)
#pragma unroll
      for (int ni = 0; ni < 4; ++ni) {
        const int rb = wc * 64 + ni * 16 + t;
        const int pb = ((kk << 2) | g) ^ (rb & 7);
        bfr[kk][ni] = *(const bf16x8*)&Bs[cur + rb * 64 + pb * 8];
      }
#pragma unroll
    for (int kk = 0; kk < 2; ++kk)
#pragma unroll
      for (int mi = 0; mi < 4; ++mi)
#pragma unroll
        for (int ni = 0; ni < 4; ++ni)
          acc[mi][ni] = MFMA16(af[kk][mi], bfr[kk][ni], acc[mi][ni]);

    __syncthreads();
  }
}

// ---------------- QKV projection ----------------
__global__ __launch_bounds__(256) void k_gemm_qkv(
    const unsigned short* __restrict__ Xb,
    const unsigned short* __restrict__ Wqt, const unsigned short* __restrict__ Wkt,
    const unsigned short* __restrict__ Wvt,
    unsigned short* __restrict__ Qb, unsigned short* __restrict__ Kb,
    unsigned short* __restrict__ Vt) {
  __shared__ alignas(16) unsigned short As[2 * 128 * 64];
  __shared__ alignas(16) unsigned short Bs[2 * 128 * 64];
  int z = blockIdx.z;
  const unsigned short* Bt = (z == 0) ? Wqt : (z == 1) ? Wkt : Wvt;
  const int wid = (blockIdx.x & 7) * 64 + (blockIdx.x >> 3);
  int tm = (wid >> 3) * 128, tn = (wid & 7) * 128;
  f32x4 acc[4][4];
  gemm_tile_lds(Xb, Bt, DMODEL, tm, tn, As, Bs, acc);

  const int lane = threadIdx.x & 63, w = threadIdx.x >> 6;
  const int wr = w >> 1, wc = w & 1, g = lane >> 4, t = lane & 15;
  if (z < 2) {
    unsigned short* O = (z == 0) ? Qb : Kb;
#pragma unroll
    for (int mi = 0; mi < 4; ++mi)
#pragma unroll
      for (int ni = 0; ni < 4; ++ni)
#pragma unroll
        for (int r = 0; r < 4; ++r) {
          int m = tm + wr * 64 + mi * 16 + g * 4 + r;
          int n = tn + wc * 64 + ni * 16 + t;
          int b = m >> 10, s = m & 1023, h = n >> 6, d = n & 63;
          O[((size_t)((b * 16 + h) * 1024 + s)) * 64 + d] = f2bf(acc[mi][ni][r]);
        }
  } else {
#pragma unroll
    for (int mi = 0; mi < 4; ++mi)
#pragma unroll
      for (int ni = 0; ni < 4; ++ni) {
        int m0 = tm + wr * 64 + mi * 16 + g * 4;
        int n = tn + wc * 64 + ni * 16 + t;
        int b = m0 >> 10, s0 = m0 & 1023, h = n >> 6, d = n & 63;
        ushort4v pk;
#pragma unroll
        for (int r = 0; r < 4; ++r) pk[r] = f2bf(acc[mi][ni][r]);
        *(ushort4v*)&Vt[((size_t)((b * 16 + h) * 64 + d) * 1024) + s0] = pk;
      }
  }
}

// ---------------- flash attention ----------------
// grid 512 (XCD-swizzled); block 512 = 8 waves; wave = 32 q-rows (256 q-rows/block).
// KVBLK=128 double-buffered LDS tiles (4x32-key halves per tile, identical compute
// order to R15 -> bit-identical); barriers 16 -> 8. Cross-lane via permlane32_swap.
__global__ __launch_bounds__(512) void k_attn(
    const unsigned short* __restrict__ Qb, const unsigned short* __restrict__ Kb,
    const unsigned short* __restrict__ Vt, const float* __restrict__ bt,
    unsigned short* __restrict__ ctx) {
  __shared__ alignas(16) unsigned short Ks[2][128 * 64];  // [key][d] swizzled, 16KB each
  __shared__ alignas(16) unsigned short Vs[2][128 * 64];  // [d][key(128)] swizzled, 16KB each
  __shared__ alignas(16) float Lb[376];                   // bias, rel in [-186,189], log2e domain
  __shared__ float sred[8][32];

  const int wid = ((blockIdx.x & 7) << 6) | (blockIdx.x >> 3);  // XCD-local head grouping
  const int bh = wid >> 2, qb = wid & 3;
  const int h = bh & 15, b = bh >> 4;
  const int tid = threadIdx.x;
  const int lane = tid & 63, w = tid >> 6;
  const int ql = lane & 31, hi = lane >> 5;
  const int q0 = qb * 256 + w * 32;
  const int q = q0 + ql;

  for (int i = tid; i < 376; i += 512) Lb[i] = bt[(size_t)h * 2048 + 837 + i];  // 837 = 1023-186

  const unsigned short* Qp = Qb + (size_t)bh * SLEN * 64;
  const unsigned short* Kp = Kb + (size_t)bh * SLEN * 64;
  const unsigned short* Vp = Vt + (size_t)bh * 64 * SLEN;

  bf16x8 bq[4];
#pragma unroll
  for (int c = 0; c < 4; ++c)
    bq[c] = *(const bf16x8*)(Qp + (size_t)q * 64 + c * 16 + hi * 8);

  const f32x16 z16 = {0.f,0.f,0.f,0.f,0.f,0.f,0.f,0.f,0.f,0.f,0.f,0.f,0.f,0.f,0.f,0.f};
  f32x16 o0 = z16, o1 = z16;
  float m = -INFINITY, l = 0.f;

  // stage a 128-key tile: K 16KB ([128 key rows][64 d], 128B rows, 8 chunks/row) and
  // V 16KB ([64 d rows][128 keys], 256B rows, 16 chunks/row). Wave w covers bytes
  // [w*2048, w*2048+2048) of each; linear LDS dest + inverse-swizzled global source
  // (chunk ^= row&7, low-3-bit XOR — bank-spread identical to R15's).
  auto stage = [&](int buf, int kbase) {
#pragma unroll
    for (int j = 0; j < 2; ++j) {
      int lb = w * 2048 + j * 1024 + lane * 16;
      int krow = lb >> 7;                          // 0..127
      int kc = ((lb >> 4) & 7) ^ (krow & 7);
      gload_lds16(Kp + (size_t)(kbase + krow) * 64 + kc * 8, &Ks[buf][w * 1024 + j * 512]);
      int vrow = lb >> 8;                          // 0..63
      int vc = ((lb >> 4) & 15) ^ (vrow & 7);
      gload_lds16(Vp + (size_t)vrow * SLEN + kbase + vc * 8, &Vs[buf][w * 1024 + j * 512]);
    }
  };

  stage(0, 0);
  __syncthreads();
  const float cpos = Lb[186 + 91], cneg = Lb[186 - 91];

  int cur = 0;
#pragma unroll 1
  for (int kt = 0; kt < 8; ++kt) {
    const int kbase = kt * 128;
    if (kt != 7) stage(cur ^ 1, kbase + 128);

    const char* Kc = (const char*)Ks[cur];
    const char* Vc = (const char*)Vs[cur];

#pragma unroll
    for (int hh = 0; hh < 4; ++hh) {
      const int kb32 = kbase + hh * 32;

      // K frags (A layout): row = hh*32+ql (0..127), logical chunk c*2+hi, swizzled
      bf16x8 ak[4];
#pragma unroll
      for (int c = 0; c < 4; ++c) {
        const int ph = ((c << 1) | hi) ^ (ql & 7);
        ak[c] = *(const bf16x8*)(Kc + (hh * 32 + ql) * 128 + ph * 16);
      }

      // V frags (B layout): row = dh*32+ql (d), logical chunk hh*4 + sl*2 + hi (0..15)
      bf16x8 bv00, bv01, bv10, bv11;
      {
        const int p0 = ((hh << 2) | hi) ^ (ql & 7);
        const int p1 = ((hh << 2) | 2 | hi) ^ (ql & 7);
        bv00 = *(const bf16x8*)(Vc + ql * 256 + p0 * 16);
        bv01 = *(const bf16x8*)(Vc + (32 + ql) * 256 + p0 * 16);
        bv10 = *(const bf16x8*)(Vc + ql * 256 + p1 * 16);
        bv11 = *(const bf16x8*)(Vc + (32 + ql) * 256 + p1 * 16);
      }

      // QK^T: S[k][q]
      f32x16 s = z16;
      __builtin_amdgcn_s_setprio(1);
#pragma unroll
      for (int c = 0; c < 4; ++c) s = MFMA32(ak[c], bq[c], s);
      __builtin_amdgcn_s_setprio(0);

      // bias in log2 domain
      const bool farp = (kb32 >= q0 + 122);
      const bool farn = (kb32 + 122 <= q0);
      if (farp || farn) {
        const float c = farp ? cpos : cneg;
#pragma unroll
        for (int r = 0; r < 16; ++r) s[r] = fmaf(s[r], LOG2E, c);
      } else {
        const int base = kb32 - q + 186 + hi * 4;
#pragma unroll
        for (int r = 0; r < 16; ++r)
          s[r] = fmaf(s[r], LOG2E, Lb[base + (r & 3) + 8 * (r >> 2)]);
      }

      // tile max: max3-shaped tree (fmax exact -> any shape bit-identical) + cross-half
      float t0 = fmaxf(fmaxf(s[0], s[1]), s[2]);
      float t1 = fmaxf(fmaxf(s[3], s[4]), s[5]);
      float t2 = fmaxf(fmaxf(s[6], s[7]), s[8]);
      float t3 = fmaxf(fmaxf(s[9], s[10]), s[11]);
      float t4 = fmaxf(fmaxf(s[12], s[13]), s[14]);
      float u0 = fmaxf(fmaxf(t0, t1), t2);
      float u1 = fmaxf(fmaxf(t3, t4), s[15]);
      float vm = xhalf_max(fmaxf(u0, u1));

      // defer-max rescale (THR=8 in log2 domain; algebraically exact)
      if (__any(vm > m + 8.0f)) {
        const float mn = fmaxf(m, vm);
        const float sc = fast_exp2(m - mn);
        m = mn;
        l *= sc;
        sred[w][ql] = sc;
        __builtin_amdgcn_wave_barrier();
#pragma unroll
        for (int r = 0; r < 16; ++r) {
          const float sr = sred[w][(r & 3) + 8 * (r >> 2) + hi * 4];
          o0[r] *= sr; o1[r] *= sr;
        }
        __builtin_amdgcn_wave_barrier();
      }

      // P = exp2(s - m), row sum (serial order preserved); cross-half sum via permlane
      float p[16];
      float ls = 0.f;
#pragma unroll
      for (int r = 0; r < 16; ++r) { p[r] = fast_exp2(s[r] - m); ls += p[r]; }
      l += xhalf_sum(ls);

      // pack P -> PV A-frags via permlane32_swap (S1 mapping, R15-verified)
      unsigned int wv[8];
#pragma unroll
      for (int i = 0; i < 8; ++i) wv[i] = cvt_pk_bf16(p[2 * i], p[2 * i + 1]);
      union { unsigned int u[4]; bf16x8 v; } pa0, pa1;
      {
        auto r02 = __builtin_amdgcn_permlane32_swap(wv[0], wv[2], false, false);
        pa0.u[0] = r02[0]; pa0.u[2] = r02[1];
        auto r13 = __builtin_amdgcn_permlane32_swap(wv[1], wv[3], false, false);
        pa0.u[1] = r13[0]; pa0.u[3] = r13[1];
        auto r46 = __builtin_amdgcn_permlane32_swap(wv[4], wv[6], false, false);
        pa1.u[0] = r46[0]; pa1.u[2] = r46[1];
        auto r57 = __builtin_amdgcn_permlane32_swap(wv[5], wv[7], false, false);
        pa1.u[1] = r57[0]; pa1.u[3] = r57[1];
      }

      // PV: O[q][d] += P[q][k] V[k][d]
      __builtin_amdgcn_s_setprio(1);
      o0 = MFMA32(pa0.v, bv00, o0);
      o0 = MFMA32(pa1.v, bv10, o0);
      o1 = MFMA32(pa0.v, bv01, o1);
      o1 = MFMA32(pa1.v, bv11, o1);
      __builtin_amdgcn_s_setprio(0);
    }

    __syncthreads();
    cur ^= 1;
  }

  // finalize
  const float inv = 1.0f / l;
  sred[w][ql] = inv;
  __builtin_amdgcn_wave_barrier();
#pragma unroll
  for (int r = 0; r < 16; ++r) {
    const float ir = sred[w][(r & 3) + 8 * (r >> 2) + hi * 4];
    const int qq = q0 + (r & 3) + 8 * (r >> 2) + hi * 4;
    const size_t base = ((size_t)(b * 1024 + qq)) * 1024 + h * 64 + ql;
    ctx[base] = f2bf(o0[r] * ir);
    ctx[base + 32] = f2bf(o1[r] * ir);
  }
}

// ---------------- output projection: out = ctx @ wo (f32 out) ----------------
__global__ __launch_bounds__(256) void k_gemm_out(
    const unsigned short* __restrict__ Cb, const unsigned short* __restrict__ Wot,
    float* __restrict__ out) {
  __shared__ alignas(16) unsigned short As[2 * 128 * 64];
  __shared__ alignas(16) unsigned short Bs[2 * 128 * 64];
  const int wid = (blockIdx.x & 7) * 64 + (blockIdx.x >> 3);  // XCD swizzle
  int tm = (wid >> 3) * 128, tn = (wid & 7) * 128;
  f32x4 acc[4][4];
  gemm_tile_lds(Cb, Wot, DMODEL, tm, tn, As, Bs, acc);

  const int lane = threadIdx.x & 63, w = threadIdx.x >> 6;
  const int wr = w >> 1, wc = w & 1, g = lane >> 4, t = lane & 15;
#pragma unroll
  for (int mi = 0; mi < 4; ++mi)
#pragma unroll
    for (int ni = 0; ni < 4; ++ni)
#pragma unroll
      for (int r = 0; r < 4; ++r) {
        int m = tm + wr * 64 + mi * 16 + g * 4 + r;
        int n = tn + wc * 64 + ni * 16 + t;
        out[(size_t)m * DMODEL + n] = acc[mi][ni][r];
      }
}

extern "C" void kernel_launch(void* const* d_in, const int* in_sizes, int n_in,
                              void* d_out, int out_size, void* d_ws, size_t ws_size,
                              hipStream_t stream) {
  const float* hs = (const float*)d_in[0];
  const float* wq = (const float*)d_in[1];
  const float* wk = (const float*)d_in[2];
  const float* wv = (const float*)d_in[3];
  const float* wo = (const float*)d_in[4];
  const float* rb = (const float*)d_in[5];

  char* ws = (char*)d_ws;
  unsigned short* Xb  = (unsigned short*)(ws + 0);          // 16 MB
  unsigned short* Wqt = (unsigned short*)(ws + 16777216);   // 2 MB
  unsigned short* Wkt = (unsigned short*)(ws + 18874368);
  unsigned short* Wvt = (unsigned short*)(ws + 20971520);
  unsigned short* Wot = (unsigned short*)(ws + 23068672);
  unsigned short* Qb  = (unsigned short*)(ws + 25165824);   // 16 MB
  unsigned short* Kb  = (unsigned short*)(ws + 41943040);   // 16 MB
  unsigned short* Vt  = (unsigned short*)(ws + 58720256);   // 16 MB
  unsigned short* Cb  = (unsigned short*)(ws + 75497472);   // 16 MB
  float* bt           = (float*)(ws + 92274688);            // 128 KB

  k_prep<<<8320, 256, 0, stream>>>(hs, Xb, wq, wk, wv, wo, Wqt, Wkt, Wvt, Wot, rb, bt);
  k_gemm_qkv<<<dim3(512, 1, 3), 256, 0, stream>>>(Xb, Wqt, Wkt, Wvt, Qb, Kb, Vt);
  k_attn<<<512, 512, 0, stream>>>(Qb, Kb, Vt, bt, Cb);
  k_gemm_out<<<512, 256, 0, stream>>>(Cb, Wot, (float*)d_out);
}

// Round 17
// 159.177 us; speedup vs baseline: 1.0615x; 1.0020x over previous
//
#include <hip/hip_runtime.h>
#include <stdint.h>

typedef __attribute__((ext_vector_type(8))) short bf16x8;
typedef __attribute__((ext_vector_type(4))) float f32x4;
typedef __attribute__((ext_vector_type(16))) float f32x16;
typedef __attribute__((ext_vector_type(8))) unsigned short ushort8;
typedef __attribute__((ext_vector_type(4))) unsigned short ushort4v;

#define MFMA16(a, b, c) __builtin_amdgcn_mfma_f32_16x16x32_bf16((a), (b), (c), 0, 0, 0)
#define MFMA32(a, b, c) __builtin_amdgcn_mfma_f32_32x32x16_bf16((a), (b), (c), 0, 0, 0)

// B=8, S=1024, D=1024, H=16, DK=64
#define SLEN 1024
#define NHEAD 16
#define HDIM 64
#define DMODEL 1024
#define NROWS 8192  // B*S
#define LOG2E 1.44269504088896340736f

__device__ __forceinline__ unsigned short f2bf(float f) {
  unsigned int u = __float_as_uint(f);
  u += 0x7FFFu + ((u >> 16) & 1u);   // RNE
  return (unsigned short)(u >> 16);
}

__device__ __forceinline__ float fast_exp2(float x) {
#if __has_builtin(__builtin_amdgcn_exp2f)
  return __builtin_amdgcn_exp2f(x);
#else
  float r; asm("v_exp_f32 %0, %1" : "=v"(r) : "v"(x)); return r;
#endif
}

__device__ __forceinline__ unsigned int cvt_pk_bf16(float lo, float hi) {
  unsigned int r;
  asm("v_cvt_pk_bf16_f32 %0, %1, %2" : "=v"(r) : "v"(lo), "v"(hi));
  return r;
}

// v_permlane32_swap (VALU): S1 semantics, returns follow operand order
// ({ret0, ret1} = {both-low-rows, both-high-rows}) — verified R15 (bit-exact pass).
// xhalf_* combine BOTH returns commutatively -> semantics-invariant.
__device__ __forceinline__ float xhalf_max(float x) {
  unsigned int u = __float_as_uint(x);
  auto r = __builtin_amdgcn_permlane32_swap(u, u, false, false);
  return fmaxf(__uint_as_float(r[0]), __uint_as_float(r[1]));
}
__device__ __forceinline__ float xhalf_sum(float x) {
  unsigned int u = __float_as_uint(x);
  auto r = __builtin_amdgcn_permlane32_swap(u, u, false, false);
  return __uint_as_float(r[0]) + __uint_as_float(r[1]);
}

// async global->LDS, 16B per lane; LDS dest = wave-uniform base + lane*16 (HW).
__device__ __forceinline__ void gload_lds16(const void* g, void* l) {
  __builtin_amdgcn_global_load_lds(
      (const __attribute__((address_space(1))) void*)g,
      (__attribute__((address_space(3))) void*)l, 16, 0, 0);
}

// ---------------- fused prep: convert X, transpose weights, bias table ----------------
__global__ __launch_bounds__(256) void k_prep(
    const float* __restrict__ x, unsigned short* __restrict__ xb,
    const float* __restrict__ w0, const float* __restrict__ w1,
    const float* __restrict__ w2, const float* __restrict__ w3,
    unsigned short* __restrict__ o0, unsigned short* __restrict__ o1,
    unsigned short* __restrict__ o2, unsigned short* __restrict__ o3,
    const float* __restrict__ rel_bias, float* __restrict__ bt) {
  const int bi = blockIdx.x;
  const int tid = threadIdx.x;
  if (bi < 4096) {
    int idx = (bi * 256 + tid) * 8;
    float4 a = *(const float4*)(x + idx);
    float4 b = *(const float4*)(x + idx + 4);
    ushort8 o;
    o[0] = f2bf(a.x); o[1] = f2bf(a.y); o[2] = f2bf(a.z); o[3] = f2bf(a.w);
    o[4] = f2bf(b.x); o[5] = f2bf(b.y); o[6] = f2bf(b.z); o[7] = f2bf(b.w);
    *(ushort8*)(xb + idx) = o;
  } else if (bi < 8192) {
    const int t = bi - 4096;
    const int z = t >> 10;
    const float* w = (z == 0) ? w0 : (z == 1) ? w1 : (z == 2) ? w2 : w3;
    unsigned short* o = (z == 0) ? o0 : (z == 1) ? o1 : (z == 2) ? o2 : o3;
    __shared__ unsigned short tile[32][33];
    const int bx = t & 31, by = (t & 1023) >> 5;
#pragma unroll
    for (int p = 0; p < 4; ++p) {
      int idx = tid + p * 256;
      int r = idx >> 5, c = idx & 31;
      tile[r][c] = f2bf(w[(size_t)(by * 32 + r) * DMODEL + bx * 32 + c]);
    }
    __syncthreads();
#pragma unroll
    for (int p = 0; p < 4; ++p) {
      int idx = tid + p * 256;
      int r = idx >> 5, c = idx & 31;
      o[(size_t)(bx * 32 + r) * DMODEL + by * 32 + c] = tile[c][r];
    }
  } else {
    int i = (bi - 8192) * 256 + tid;
    if (i >= NHEAD * 2047) return;
    int h = i / 2047, rdx = i % 2047;
    int rel = rdx - 1023;
    int rb = (rel > 0) ? 16 : 0;
    int rp = (rel < 0) ? -rel : rel;
    int bucket;
    if (rp < 8) {
      bucket = rb + rp;
    } else {
      int large;
      if (rp >= 91) {
        large = 15;
      } else {
        int nb = 31 - __clz(rp);
        long long sq = (long long)rp * rp;
        int f2 = 2 * nb + ((sq >= (1LL << (2 * nb + 1))) ? 1 : 0);
        large = 8 + (f2 - 6);
        if (large > 15) large = 15;
      }
      bucket = rb + large;
    }
    bt[h * 2048 + rdx] = rel_bias[bucket * 16 + h] * LOG2E;
  }
}

// ---------------- 2-phase GEMM core, BK=64, XOR-swizzled LDS (R10-verified) ----------------
__device__ __forceinline__ void gemm_tile_lds(const unsigned short* __restrict__ A,
                                              const unsigned short* __restrict__ Bt,
                                              int K, int tm, int tn,
                                              unsigned short* As, unsigned short* Bs,
                                              f32x4 acc[4][4]) {
  const int tid = threadIdx.x;
  const int lane = tid & 63;
  const int w = tid >> 6;
  const int wr = w >> 1, wc = w & 1;
  const int g = lane >> 4, t = lane & 15;
  const int NKT = K >> 6;   // BK=64

  auto stageT = [&](int bufo, int ko) {
#pragma unroll
    for (int j = 0; j < 4; ++j) {
      const int r = w * 32 + j * 8 + (lane >> 3);
      const int lc = (lane & 7) ^ (r & 7);
      gload_lds16(A + (size_t)(tm + r) * K + ko + lc * 8, As + bufo + (w * 4 + j) * 512);
      gload_lds16(Bt + (size_t)(tn + r) * K + ko + lc * 8, Bs + bufo + (w * 4 + j) * 512);
    }
  };

  f32x4 z = {0.f, 0.f, 0.f, 0.f};
#pragma unroll
  for (int mi = 0; mi < 4; ++mi)
#pragma unroll
    for (int ni = 0; ni < 4; ++ni) acc[mi][ni] = z;

  stageT(0, 0);
  __syncthreads();

#pragma unroll 1
  for (int kt = 0; kt < NKT; ++kt) {
    const int cur = (kt & 1) * 8192;
    if (kt + 1 < NKT) stageT(cur ^ 8192, (kt + 1) * 64);

    bf16x8 af[2][4], bfr[2][4];
#pragma unroll
    for (int kk = 0; kk < 2; ++kk)
#pragma unroll
      for (int mi = 0; mi < 4; ++mi) {
        const int ra = wr * 64 + mi * 16 + t;
        const int pa = ((kk << 2) | g) ^ (ra & 7);
        af[kk][mi] = *(const bf16x8*)&As[cur + ra * 64 + pa * 8];
      }
#pragma unroll
    for (int kk = 0; kk < 2; ++kk)
#pragma unroll
      for (int ni = 0; ni < 4; ++ni) {
        const int rb = wc * 64 + ni * 16 + t;
        const int pb = ((kk << 2) | g) ^ (rb & 7);
        bfr[kk][ni] = *(const bf16x8*)&Bs[cur + rb * 64 + pb * 8];
      }
#pragma unroll
    for (int kk = 0; kk < 2; ++kk)
#pragma unroll
      for (int mi = 0; mi < 4; ++mi)
#pragma unroll
        for (int ni = 0; ni < 4; ++ni)
          acc[mi][ni] = MFMA16(af[kk][mi], bfr[kk][ni], acc[mi][ni]);

    __syncthreads();
  }
}

// ---------------- QKV projection ----------------
__global__ __launch_bounds__(256) void k_gemm_qkv(
    const unsigned short* __restrict__ Xb,
    const unsigned short* __restrict__ Wqt, const unsigned short* __restrict__ Wkt,
    const unsigned short* __restrict__ Wvt,
    unsigned short* __restrict__ Qb, unsigned short* __restrict__ Kb,
    unsigned short* __restrict__ Vt) {
  __shared__ alignas(16) unsigned short As[2 * 128 * 64];
  __shared__ alignas(16) unsigned short Bs[2 * 128 * 64];
  int z = blockIdx.z;
  const unsigned short* Bt = (z == 0) ? Wqt : (z == 1) ? Wkt : Wvt;
  const int wid = (blockIdx.x & 7) * 64 + (blockIdx.x >> 3);
  int tm = (wid >> 3) * 128, tn = (wid & 7) * 128;
  f32x4 acc[4][4];
  gemm_tile_lds(Xb, Bt, DMODEL, tm, tn, As, Bs, acc);

  const int lane = threadIdx.x & 63, w = threadIdx.x >> 6;
  const int wr = w >> 1, wc = w & 1, g = lane >> 4, t = lane & 15;
  if (z < 2) {
    unsigned short* O = (z == 0) ? Qb : Kb;
#pragma unroll
    for (int mi = 0; mi < 4; ++mi)
#pragma unroll
      for (int ni = 0; ni < 4; ++ni)
#pragma unroll
        for (int r = 0; r < 4; ++r) {
          int m = tm + wr * 64 + mi * 16 + g * 4 + r;
          int n = tn + wc * 64 + ni * 16 + t;
          int b = m >> 10, s = m & 1023, h = n >> 6, d = n & 63;
          O[((size_t)((b * 16 + h) * 1024 + s)) * 64 + d] = f2bf(acc[mi][ni][r]);
        }
  } else {
#pragma unroll
    for (int mi = 0; mi < 4; ++mi)
#pragma unroll
      for (int ni = 0; ni < 4; ++ni) {
        int m0 = tm + wr * 64 + mi * 16 + g * 4;
        int n = tn + wc * 64 + ni * 16 + t;
        int b = m0 >> 10, s0 = m0 & 1023, h = n >> 6, d = n & 63;
        ushort4v pk;
#pragma unroll
        for (int r = 0; r < 4; ++r) pk[r] = f2bf(acc[mi][ni][r]);
        *(ushort4v*)&Vt[((size_t)((b * 16 + h) * 64 + d) * 1024) + s0] = pk;
      }
  }
}

// ---------------- flash attention ----------------
// grid 512 (XCD-swizzled); block 512 = 8 waves; wave = 32 q-rows (256 q-rows/block).
// KVBLK=128 double-buffered LDS tiles; cross-lane via permlane32_swap (R15/R16-verified).
// R17: ls accumulated via depth-4 balanced tree (deliberate reassociation; margin-audited).
__global__ __launch_bounds__(512) void k_attn(
    const unsigned short* __restrict__ Qb, const unsigned short* __restrict__ Kb,
    const unsigned short* __restrict__ Vt, const float* __restrict__ bt,
    unsigned short* __restrict__ ctx) {
  __shared__ alignas(16) unsigned short Ks[2][128 * 64];  // [key][d] swizzled, 16KB each
  __shared__ alignas(16) unsigned short Vs[2][128 * 64];  // [d][key(128)] swizzled, 16KB each
  __shared__ alignas(16) float Lb[376];                   // bias, rel in [-186,189], log2e domain
  __shared__ float sred[8][32];

  const int wid = ((blockIdx.x & 7) << 6) | (blockIdx.x >> 3);  // XCD-local head grouping
  const int bh = wid >> 2, qb = wid & 3;
  const int h = bh & 15, b = bh >> 4;
  const int tid = threadIdx.x;
  const int lane = tid & 63, w = tid >> 6;
  const int ql = lane & 31, hi = lane >> 5;
  const int q0 = qb * 256 + w * 32;
  const int q = q0 + ql;

  for (int i = tid; i < 376; i += 512) Lb[i] = bt[(size_t)h * 2048 + 837 + i];  // 837 = 1023-186

  const unsigned short* Qp = Qb + (size_t)bh * SLEN * 64;
  const unsigned short* Kp = Kb + (size_t)bh * SLEN * 64;
  const unsigned short* Vp = Vt + (size_t)bh * 64 * SLEN;

  bf16x8 bq[4];
#pragma unroll
  for (int c = 0; c < 4; ++c)
    bq[c] = *(const bf16x8*)(Qp + (size_t)q * 64 + c * 16 + hi * 8);

  const f32x16 z16 = {0.f,0.f,0.f,0.f,0.f,0.f,0.f,0.f,0.f,0.f,0.f,0.f,0.f,0.f,0.f,0.f};
  f32x16 o0 = z16, o1 = z16;
  float m = -INFINITY, l = 0.f;

  auto stage = [&](int buf, int kbase) {
#pragma unroll
    for (int j = 0; j < 2; ++j) {
      int lb = w * 2048 + j * 1024 + lane * 16;
      int krow = lb >> 7;                          // 0..127
      int kc = ((lb >> 4) & 7) ^ (krow & 7);
      gload_lds16(Kp + (size_t)(kbase + krow) * 64 + kc * 8, &Ks[buf][w * 1024 + j * 512]);
      int vrow = lb >> 8;                          // 0..63
      int vc = ((lb >> 4) & 15) ^ (vrow & 7);
      gload_lds16(Vp + (size_t)vrow * SLEN + kbase + vc * 8, &Vs[buf][w * 1024 + j * 512]);
    }
  };

  stage(0, 0);
  __syncthreads();
  const float cpos = Lb[186 + 91], cneg = Lb[186 - 91];

  int cur = 0;
#pragma unroll 1
  for (int kt = 0; kt < 8; ++kt) {
    const int kbase = kt * 128;
    if (kt != 7) stage(cur ^ 1, kbase + 128);

    const char* Kc = (const char*)Ks[cur];
    const char* Vc = (const char*)Vs[cur];

#pragma unroll
    for (int hh = 0; hh < 4; ++hh) {
      const int kb32 = kbase + hh * 32;

      bf16x8 ak[4];
#pragma unroll
      for (int c = 0; c < 4; ++c) {
        const int ph = ((c << 1) | hi) ^ (ql & 7);
        ak[c] = *(const bf16x8*)(Kc + (hh * 32 + ql) * 128 + ph * 16);
      }

      bf16x8 bv00, bv01, bv10, bv11;
      {
        const int p0 = ((hh << 2) | hi) ^ (ql & 7);
        const int p1 = ((hh << 2) | 2 | hi) ^ (ql & 7);
        bv00 = *(const bf16x8*)(Vc + ql * 256 + p0 * 16);
        bv01 = *(const bf16x8*)(Vc + (32 + ql) * 256 + p0 * 16);
        bv10 = *(const bf16x8*)(Vc + ql * 256 + p1 * 16);
        bv11 = *(const bf16x8*)(Vc + (32 + ql) * 256 + p1 * 16);
      }

      // QK^T: S[k][q]
      f32x16 s = z16;
      __builtin_amdgcn_s_setprio(1);
#pragma unroll
      for (int c = 0; c < 4; ++c) s = MFMA32(ak[c], bq[c], s);
      __builtin_amdgcn_s_setprio(0);

      // bias in log2 domain
      const bool farp = (kb32 >= q0 + 122);
      const bool farn = (kb32 + 122 <= q0);
      if (farp || farn) {
        const float c = farp ? cpos : cneg;
#pragma unroll
        for (int r = 0; r < 16; ++r) s[r] = fmaf(s[r], LOG2E, c);
      } else {
        const int base = kb32 - q + 186 + hi * 4;
#pragma unroll
        for (int r = 0; r < 16; ++r)
          s[r] = fmaf(s[r], LOG2E, Lb[base + (r & 3) + 8 * (r >> 2)]);
      }

      // tile max: max3-shaped tree (fmax exact) + cross-half via permlane
      float t0 = fmaxf(fmaxf(s[0], s[1]), s[2]);
      float t1 = fmaxf(fmaxf(s[3], s[4]), s[5]);
      float t2 = fmaxf(fmaxf(s[6], s[7]), s[8]);
      float t3 = fmaxf(fmaxf(s[9], s[10]), s[11]);
      float t4 = fmaxf(fmaxf(s[12], s[13]), s[14]);
      float u0 = fmaxf(fmaxf(t0, t1), t2);
      float u1 = fmaxf(fmaxf(t3, t4), s[15]);
      float vm = xhalf_max(fmaxf(u0, u1));

      // defer-max rescale (THR=8 in log2 domain; algebraically exact)
      if (__any(vm > m + 8.0f)) {
        const float mn = fmaxf(m, vm);
        const float sc = fast_exp2(m - mn);
        m = mn;
        l *= sc;
        sred[w][ql] = sc;
        __builtin_amdgcn_wave_barrier();
#pragma unroll
        for (int r = 0; r < 16; ++r) {
          const float sr = sred[w][(r & 3) + 8 * (r >> 2) + hi * 4];
          o0[r] *= sr; o1[r] *= sr;
        }
        __builtin_amdgcn_wave_barrier();
      }

      // P = exp2(s - m); ls via depth-4 balanced tree (reassociated; ~2e-6 rel shift of l,
      // 30x under the absmax margin — see R17 analysis)
      float p[16];
#pragma unroll
      for (int r = 0; r < 16; ++r) p[r] = fast_exp2(s[r] - m);
      {
        float a0 = p[0] + p[1], a1 = p[2] + p[3], a2 = p[4] + p[5], a3 = p[6] + p[7];
        float a4 = p[8] + p[9], a5 = p[10] + p[11], a6 = p[12] + p[13], a7 = p[14] + p[15];
        float b0 = a0 + a1, b1 = a2 + a3, b2 = a4 + a5, b3 = a6 + a7;
        float ls = (b0 + b1) + (b2 + b3);
        l += xhalf_sum(ls);
      }

      // pack P -> PV A-frags via permlane32_swap (S1 mapping, R15-verified)
      unsigned int wv[8];
#pragma unroll
      for (int i = 0; i < 8; ++i) wv[i] = cvt_pk_bf16(p[2 * i], p[2 * i + 1]);
      union { unsigned int u[4]; bf16x8 v; } pa0, pa1;
      {
        auto r02 = __builtin_amdgcn_permlane32_swap(wv[0], wv[2], false, false);
        pa0.u[0] = r02[0]; pa0.u[2] = r02[1];
        auto r13 = __builtin_amdgcn_permlane32_swap(wv[1], wv[3], false, false);
        pa0.u[1] = r13[0]; pa0.u[3] = r13[1];
        auto r46 = __builtin_amdgcn_permlane32_swap(wv[4], wv[6], false, false);
        pa1.u[0] = r46[0]; pa1.u[2] = r46[1];
        auto r57 = __builtin_amdgcn_permlane32_swap(wv[5], wv[7], false, false);
        pa1.u[1] = r57[0]; pa1.u[3] = r57[1];
      }

      // PV: O[q][d] += P[q][k] V[k][d]
      __builtin_amdgcn_s_setprio(1);
      o0 = MFMA32(pa0.v, bv00, o0);
      o0 = MFMA32(pa1.v, bv10, o0);
      o1 = MFMA32(pa0.v, bv01, o1);
      o1 = MFMA32(pa1.v, bv11, o1);
      __builtin_amdgcn_s_setprio(0);
    }

    __syncthreads();
    cur ^= 1;
  }

  // finalize
  const float inv = 1.0f / l;
  sred[w][ql] = inv;
  __builtin_amdgcn_wave_barrier();
#pragma unroll
  for (int r = 0; r < 16; ++r) {
    const float ir = sred[w][(r & 3) + 8 * (r >> 2) + hi * 4];
    const int qq = q0 + (r & 3) + 8 * (r >> 2) + hi * 4;
    const size_t base = ((size_t)(b * 1024 + qq)) * 1024 + h * 64 + ql;
    ctx[base] = f2bf(o0[r] * ir);
    ctx[base + 32] = f2bf(o1[r] * ir);
  }
}

// ---------------- output projection: out = ctx @ wo (f32 out) ----------------
__global__ __launch_bounds__(256) void k_gemm_out(
    const unsigned short* __restrict__ Cb, const unsigned short* __restrict__ Wot,
    float* __restrict__ out) {
  __shared__ alignas(16) unsigned short As[2 * 128 * 64];
  __shared__ alignas(16) unsigned short Bs[2 * 128 * 64];
  const int wid = (blockIdx.x & 7) * 64 + (blockIdx.x >> 3);  // XCD swizzle
  int tm = (wid >> 3) * 128, tn = (wid & 7) * 128;
  f32x4 acc[4][4];
  gemm_tile_lds(Cb, Wot, DMODEL, tm, tn, As, Bs, acc);

  const int lane = threadIdx.x & 63, w = threadIdx.x >> 6;
  const int wr = w >> 1, wc = w & 1, g = lane >> 4, t = lane & 15;
#pragma unroll
  for (int mi = 0; mi < 4; ++mi)
#pragma unroll
    for (int ni = 0; ni < 4; ++ni)
#pragma unroll
      for (int r = 0; r < 4; ++r) {
        int m = tm + wr * 64 + mi * 16 + g * 4 + r;
        int n = tn + wc * 64 + ni * 16 + t;
        out[(size_t)m * DMODEL + n] = acc[mi][ni][r];
      }
}

extern "C" void kernel_launch(void* const* d_in, const int* in_sizes, int n_in,
                              void* d_out, int out_size, void* d_ws, size_t ws_size,
                              hipStream_t stream) {
  const float* hs = (const float*)d_in[0];
  const float* wq = (const float*)d_in[1];
  const float* wk = (const float*)d_in[2];
  const float* wv = (const float*)d_in[3];
  const float* wo = (const float*)d_in[4];
  const float* rb = (const float*)d_in[5];

  char* ws = (char*)d_ws;
  unsigned short* Xb  = (unsigned short*)(ws + 0);          // 16 MB
  unsigned short* Wqt = (unsigned short*)(ws + 16777216);   // 2 MB
  unsigned short* Wkt = (unsigned short*)(ws + 18874368);
  unsigned short* Wvt = (unsigned short*)(ws + 20971520);
  unsigned short* Wot = (unsigned short*)(ws + 23068672);
  unsigned short* Qb  = (unsigned short*)(ws + 25165824);   // 16 MB
  unsigned short* Kb  = (unsigned short*)(ws + 41943040);   // 16 MB
  unsigned short* Vt  = (unsigned short*)(ws + 58720256);   // 16 MB
  unsigned short* Cb  = (unsigned short*)(ws + 75497472);   // 16 MB
  float* bt           = (float*)(ws + 92274688);            // 128 KB

  k_prep<<<8320, 256, 0, stream>>>(hs, Xb, wq, wk, wv, wo, Wqt, Wkt, Wvt, Wot, rb, bt);
  k_gemm_qkv<<<dim3(512, 1, 3), 256, 0, stream>>>(Xb, Wqt, Wkt, Wvt, Qb, Kb, Vt);
  k_attn<<<512, 512, 0, stream>>>(Qb, Kb, Vt, bt, Cb);
  k_gemm_out<<<512, 256, 0, stream>>>(Cb, Wot, (float*)d_out);
}